// Round 1
// baseline (233.452 us; speedup 1.0000x reference)
//
#include <hip/hip_runtime.h>
#include <hip/hip_bf16.h>
#include <stdint.h>
#include <math.h>

// B=2, T=2048, D=1024, H=16, DH=64
#define T_SEQ 2048
#define NHEAD 16
#define NBH   32      // B*H
#define BTROW 4096    // B*T

typedef __bf16 bf16_t;
typedef __bf16 bf16x4_t __attribute__((ext_vector_type(4)));
typedef __bf16 bf16x8_t __attribute__((ext_vector_type(8)));
typedef float  f32x4_t  __attribute__((ext_vector_type(4)));

__device__ __forceinline__ f32x4_t mfma16(bf16x8_t a, bf16x8_t b, f32x4_t c) {
  return __builtin_amdgcn_mfma_f32_16x16x32_bf16(a, b, c, 0, 0, 0);
}

// async global->LDS, 16B per lane; lds dest must be wave-uniform base (HW adds lane*16)
__device__ __forceinline__ void gl_lds16(const bf16_t* g, bf16_t* l) {
  __builtin_amdgcn_global_load_lds(
      (const __attribute__((address_space(1))) void*)g,
      (__attribute__((address_space(3))) void*)l, 16, 0, 0);
}

// ---------------- cast f32 -> bf16 (vectorized) ----------------
__global__ __launch_bounds__(256) void k_cast_bf16(const float* __restrict__ in,
                                                   bf16_t* __restrict__ out, int n) {
  int tid = blockIdx.x * blockDim.x + threadIdx.x;
  int stride = gridDim.x * blockDim.x;
  for (int i = tid * 4; i < n; i += stride * 4) {
    float4 a = *(const float4*)(in + i);
    bf16x4_t r = { (bf16_t)a.x, (bf16_t)a.y, (bf16_t)a.z, (bf16_t)a.w };
    *(bf16x4_t*)(out + i) = r;
  }
}

// ---------------- transpose + cast: W[K][N] f32 -> WT[N][K] bf16 ----------------
__global__ __launch_bounds__(256) void k_trans_cast(const float* __restrict__ W,
                                                    bf16_t* __restrict__ WT,
                                                    int K, int N) {
  __shared__ float tile[32][33];
  int n0 = blockIdx.x * 32, k0 = blockIdx.y * 32;
  int tx = threadIdx.x & 31, ty = threadIdx.x >> 5;  // 32 x 8
#pragma unroll
  for (int j = 0; j < 4; j++)
    tile[ty + j * 8][tx] = W[(size_t)(k0 + ty + j * 8) * N + n0 + tx];
  __syncthreads();
#pragma unroll
  for (int j = 0; j < 4; j++)
    WT[(size_t)(n0 + ty + j * 8) * K + k0 + tx] = (bf16_t)tile[tx][ty + j * 8];
}

// ---------------- RoPE cos/sin table [T][32] f32 ----------------
__global__ __launch_bounds__(256) void k_rope_table(float* __restrict__ cs,
                                                    float* __restrict__ sn) {
  int i = blockIdx.x * blockDim.x + threadIdx.x;  // t*32 + j
  if (i >= T_SEQ * 32) return;
  int t = i >> 5, j = i & 31;
  float inv = powf(10000.0f, -(float)(2 * j) / 64.0f);
  float f = (float)t * inv;
  cs[i] = cosf(f);
  sn[i] = sinf(f);
}

// ---------------- GEMM: C[M][N] = A[M][K] * BT[N][K]^T  (bf16 in, OUT out) ----------
// 128x128 tile, BK=32, 256 threads (4 waves, 2x2), each wave 64x64 via 4x4 16x16x32.
template <typename OUT>
__global__ __launch_bounds__(256) void k_gemm_bt(const bf16_t* __restrict__ A,
                                                 const bf16_t* __restrict__ Bt,
                                                 OUT* __restrict__ C,
                                                 int M, int N, int K) {
  __shared__ __align__(16) bf16_t As[128 * 32];
  __shared__ __align__(16) bf16_t Bs[128 * 32];
  int m0 = blockIdx.y * 128, n0 = blockIdx.x * 128;
  int tid = threadIdx.x;
  int lane = tid & 63, w = tid >> 6;
  int wr = w >> 1, wc = w & 1;
  int l15 = lane & 15, l4 = lane >> 4;

  f32x4_t acc[4][4];
#pragma unroll
  for (int m = 0; m < 4; m++)
#pragma unroll
    for (int n = 0; n < 4; n++) acc[m][n] = (f32x4_t){0.f, 0.f, 0.f, 0.f};

  for (int k0 = 0; k0 < K; k0 += 32) {
#pragma unroll
    for (int j = 0; j < 2; j++) {
      int c = j * 256 + tid;          // chunk id, 512 chunks of 16B per tile
      int row = c >> 2, kb = c & 3;   // 4 chunks per 32-elem row
      gl_lds16(A + (size_t)(m0 + row) * K + k0 + kb * 8, As + (size_t)(j * 256 + w * 64) * 8);
      gl_lds16(Bt + (size_t)(n0 + row) * K + k0 + kb * 8, Bs + (size_t)(j * 256 + w * 64) * 8);
    }
    __syncthreads();
    bf16x8_t af[4], bfr[4];
#pragma unroll
    for (int m = 0; m < 4; m++)
      af[m] = *(const bf16x8_t*)(As + (size_t)(wr * 64 + m * 16 + l15) * 32 + l4 * 8);
#pragma unroll
    for (int n = 0; n < 4; n++)
      bfr[n] = *(const bf16x8_t*)(Bs + (size_t)(wc * 64 + n * 16 + l15) * 32 + l4 * 8);
#pragma unroll
    for (int m = 0; m < 4; m++)
#pragma unroll
      for (int n = 0; n < 4; n++) acc[m][n] = mfma16(af[m], bfr[n], acc[m][n]);
    __syncthreads();
  }
#pragma unroll
  for (int m = 0; m < 4; m++)
#pragma unroll
    for (int n = 0; n < 4; n++)
#pragma unroll
      for (int r = 0; r < 4; r++) {
        int row = m0 + wr * 64 + m * 16 + l4 * 4 + r;
        int col = n0 + wc * 64 + n * 16 + l15;
        C[(size_t)row * N + col] = (OUT)acc[m][n][r];
      }
}

// ---------------- RoPE + relayout ----------------
// qkv [BT][3072] bf16 -> Qr,Kr [bh][t][64] (Q scaled by 0.125), Vt [bh][64][t]
__global__ __launch_bounds__(256) void k_rope_layout(const bf16_t* __restrict__ qkv,
                                                     const float* __restrict__ cs,
                                                     const float* __restrict__ sn,
                                                     bf16_t* __restrict__ Qr,
                                                     bf16_t* __restrict__ Kr,
                                                     bf16_t* __restrict__ Vt) {
  int tb = blockIdx.x, bh = blockIdx.y;
  int b = bh >> 4, h = bh & 15;
  int t0 = tb * 64;
  int tid = threadIdx.x;
  int j = tid & 31, tl = tid >> 5;  // j: rot pair, tl: row 0..7

#pragma unroll
  for (int p = 0; p < 8; p++) {
    int t = t0 + p * 8 + tl;
    size_t rowoff = (size_t)(b * T_SEQ + t) * 3072;
    float c = cs[t * 32 + j], s = sn[t * 32 + j];
    size_t qo = ((size_t)bh * T_SEQ + t) * 64;
    // Q (scaled by 1/8 = exact in bf16)
    float x1 = (float)qkv[rowoff + h * 64 + j];
    float x2 = (float)qkv[rowoff + h * 64 + 32 + j];
    Qr[qo + j]      = (bf16_t)((x1 * c - x2 * s) * 0.125f);
    Qr[qo + 32 + j] = (bf16_t)((x1 * s + x2 * c) * 0.125f);
    // K
    x1 = (float)qkv[rowoff + 1024 + h * 64 + j];
    x2 = (float)qkv[rowoff + 1024 + h * 64 + 32 + j];
    Kr[qo + j]      = (bf16_t)(x1 * c - x2 * s);
    Kr[qo + 32 + j] = (bf16_t)(x1 * s + x2 * c);
  }

  // V: [t][dh] -> Vt[bh][dh][t] via LDS tile
  __shared__ bf16_t vt[64][65];
#pragma unroll
  for (int p = 0; p < 16; p++) {
    int idx = p * 256 + tid;
    int tl2 = idx >> 6, d = idx & 63;
    vt[d][tl2] = qkv[(size_t)(b * T_SEQ + t0 + tl2) * 3072 + 2048 + h * 64 + d];
  }
  __syncthreads();
#pragma unroll
  for (int p = 0; p < 16; p++) {
    int idx = p * 256 + tid;
    int d = idx >> 6, tl2 = idx & 63;
    Vt[((size_t)bh * 64 + d) * T_SEQ + t0 + tl2] = vt[d][tl2];
  }
}

// ---------------- flash attention ----------------
// grid: (T/64, B*H). 4 waves, each 16 q-rows. KV tiles of 64. Causal.
__global__ __launch_bounds__(256) void k_attn(const bf16_t* __restrict__ Qr,
                                              const bf16_t* __restrict__ Kr,
                                              const bf16_t* __restrict__ Vt,
                                              bf16_t* __restrict__ Ob) {
  __shared__ __align__(16) bf16_t Ks[64 * 64];
  __shared__ __align__(16) bf16_t Vs[64 * 64];
  __shared__ __align__(16) bf16_t Ps[4 * 16 * 64];
  int qb = blockIdx.x, bh = blockIdx.y;
  int b = bh >> 4, h = bh & 15;
  int q0 = qb * 64;
  int tid = threadIdx.x, lane = tid & 63, w = tid >> 6;
  int l15 = lane & 15, l4 = lane >> 4;

  // Q fragments (A-operand): row = l15 (q within wave tile), k = 8*l4+i (+32*ks)
  bf16x8_t qf[2];
  size_t qbase = ((size_t)bh * T_SEQ + q0 + w * 16 + l15) * 64;
  qf[0] = *(const bf16x8_t*)(Qr + qbase + l4 * 8);
  qf[1] = *(const bf16x8_t*)(Qr + qbase + 32 + l4 * 8);

  f32x4_t o[4];
#pragma unroll
  for (int n = 0; n < 4; n++) o[n] = (f32x4_t){0.f, 0.f, 0.f, 0.f};
  float mrow[4] = {-1e30f, -1e30f, -1e30f, -1e30f};
  float lrow[4] = {0.f, 0.f, 0.f, 0.f};

  const bf16_t* Kbh = Kr + (size_t)bh * T_SEQ * 64;
  const bf16_t* Vbh = Vt + (size_t)bh * 64 * T_SEQ;

  for (int it = 0; it <= qb; it++) {
    int kb = it * 64;
    // stage K tile [64][64] and V^T tile [64 dh][64 kv]; 512 chunks each
#pragma unroll
    for (int j = 0; j < 2; j++) {
      int c = j * 256 + tid;
      int row = c >> 3, k8 = c & 7;  // 8 chunks per 64-elem row
      gl_lds16(Kbh + (size_t)(kb + row) * 64 + k8 * 8, Ks + (size_t)(j * 256 + w * 64) * 8);
      gl_lds16(Vbh + (size_t)row * T_SEQ + kb + k8 * 8, Vs + (size_t)(j * 256 + w * 64) * 8);
    }
    __syncthreads();

    // S = Q K^T (scale pre-folded into Q)
    f32x4_t s[4];
#pragma unroll
    for (int n = 0; n < 4; n++) {
      bf16x8_t kf0 = *(const bf16x8_t*)(Ks + (size_t)(n * 16 + l15) * 64 + l4 * 8);
      bf16x8_t kf1 = *(const bf16x8_t*)(Ks + (size_t)(n * 16 + l15) * 64 + 32 + l4 * 8);
      s[n] = (f32x4_t){0.f, 0.f, 0.f, 0.f};
      s[n] = mfma16(qf[0], kf0, s[n]);
      s[n] = mfma16(qf[1], kf1, s[n]);
    }

    if (it == qb) {  // diagonal tile: causal mask
#pragma unroll
      for (int n = 0; n < 4; n++)
#pragma unroll
        for (int r = 0; r < 4; r++) {
          int kv = kb + n * 16 + l15;
          int q = q0 + w * 16 + l4 * 4 + r;
          if (kv > q) s[n][r] = -1e30f;
        }
    }

    // online softmax (rows live across 16-lane groups)
#pragma unroll
    for (int r = 0; r < 4; r++) {
      float mx = fmaxf(fmaxf(s[0][r], s[1][r]), fmaxf(s[2][r], s[3][r]));
#pragma unroll
      for (int d = 8; d >= 1; d >>= 1) mx = fmaxf(mx, __shfl_xor(mx, d, 64));
      float mnew = fmaxf(mrow[r], mx);
      float alpha = __expf(mrow[r] - mnew);
      mrow[r] = mnew;
      float sum = 0.f;
#pragma unroll
      for (int n = 0; n < 4; n++) {
        float p = __expf(s[n][r] - mnew);
        s[n][r] = p;
        sum += p;
      }
#pragma unroll
      for (int d = 8; d >= 1; d >>= 1) sum += __shfl_xor(sum, d, 64);
      lrow[r] = lrow[r] * alpha + sum;
#pragma unroll
      for (int n = 0; n < 4; n++) o[n][r] *= alpha;
#pragma unroll
      for (int n = 0; n < 4; n++)
        Ps[(size_t)(w * 16 + l4 * 4 + r) * 64 + n * 16 + l15] = (bf16_t)s[n][r];
    }
    __syncthreads();

    // O += P V : A = P[q][kv], B = V[kv][dh] read from Vs[dh][kv]
#pragma unroll
    for (int ks = 0; ks < 2; ks++) {
      bf16x8_t pa = *(const bf16x8_t*)(Ps + (size_t)(w * 16 + l15) * 64 + ks * 32 + l4 * 8);
#pragma unroll
      for (int n = 0; n < 4; n++) {
        bf16x8_t vf = *(const bf16x8_t*)(Vs + (size_t)(n * 16 + l15) * 64 + ks * 32 + l4 * 8);
        o[n] = mfma16(pa, vf, o[n]);
      }
    }
    __syncthreads();
  }

  // epilogue: Ob[b*T+q][h*64+dh] = O / l
#pragma unroll
  for (int r = 0; r < 4; r++) {
    float inv = 1.0f / lrow[r];
    int q = q0 + w * 16 + l4 * 4 + r;
    size_t off = ((size_t)(b * T_SEQ + q)) * 1024 + h * 64;
#pragma unroll
    for (int n = 0; n < 4; n++)
      Ob[off + n * 16 + l15] = (bf16_t)(o[n][r] * inv);
  }
}

// ---------------- launch ----------------
extern "C" void kernel_launch(void* const* d_in, const int* in_sizes, int n_in,
                              void* d_out, int out_size, void* d_ws, size_t ws_size,
                              hipStream_t stream) {
  const float* x    = (const float*)d_in[0];
  const float* Wqkv = (const float*)d_in[1];
  const float* Wout = (const float*)d_in[2];
  float* out = (float*)d_out;
  char* ws = (char*)d_ws;

  // ws layout (bytes); total ~64.5 MB
  bf16_t* wqkvT = (bf16_t*)(ws + 0);                       // [3072][1024] 6 MB
  bf16_t* woutT = (bf16_t*)(ws + 6291456);                 // [1024][1024] 2 MB
  bf16_t* xb    = (bf16_t*)(ws + 8388608);                 // [4096][1024] 8 MB (reused as Ob)
  bf16_t* qkv   = (bf16_t*)(ws + 16777216);                // [4096][3072] 24 MB
  bf16_t* Qr    = (bf16_t*)(ws + 41943040);                // [32][2048][64] 8 MB
  bf16_t* Kr    = (bf16_t*)(ws + 50331648);                // 8 MB
  bf16_t* Vt    = (bf16_t*)(ws + 58720256);                // [32][64][2048] 8 MB
  float*  cs    = (float*)(ws + 67108864);                 // [2048][32] 256 KB
  float*  sn    = (float*)(ws + 67371008);                 // 256 KB
  bf16_t* Ob    = xb;  // xb dead after GEMM1

  k_cast_bf16<<<2048, 256, 0, stream>>>(x, xb, 4096 * 1024);
  k_trans_cast<<<dim3(3072 / 32, 1024 / 32), 256, 0, stream>>>(Wqkv, wqkvT, 1024, 3072);
  k_trans_cast<<<dim3(1024 / 32, 1024 / 32), 256, 0, stream>>>(Wout, woutT, 1024, 1024);
  k_rope_table<<<(T_SEQ * 32) / 256, 256, 0, stream>>>(cs, sn);

  k_gemm_bt<bf16_t><<<dim3(3072 / 128, 4096 / 128), 256, 0, stream>>>(xb, wqkvT, qkv,
                                                                      4096, 3072, 1024);
  k_rope_layout<<<dim3(T_SEQ / 64, NBH), 256, 0, stream>>>(qkv, cs, sn, Qr, Kr, Vt);
  k_attn<<<dim3(T_SEQ / 64, NBH), 256, 0, stream>>>(Qr, Kr, Vt, Ob);
  k_gemm_bt<float><<<dim3(1024 / 128, 4096 / 128), 256, 0, stream>>>(Ob, woutT, out,
                                                                     4096, 1024, 1024);
}

// Round 2
// 175.128 us; speedup vs baseline: 1.3330x; 1.3330x over previous
//
#include <hip/hip_runtime.h>
#include <hip/hip_bf16.h>
#include <stdint.h>
#include <math.h>

// B=2, T=2048, D=1024, H=16, DH=64
#define T_SEQ 2048
#define NHEAD 16
#define NBH   32      // B*H
#define BTROW 4096    // B*T

typedef __bf16 bf16_t;
typedef __bf16 bf16x4_t __attribute__((ext_vector_type(4)));
typedef __bf16 bf16x8_t __attribute__((ext_vector_type(8)));
typedef float  f32x4_t  __attribute__((ext_vector_type(4)));

__device__ __forceinline__ f32x4_t mfma16(bf16x8_t a, bf16x8_t b, f32x4_t c) {
  return __builtin_amdgcn_mfma_f32_16x16x32_bf16(a, b, c, 0, 0, 0);
}

// async global->LDS, 16B per lane; lds dest is wave-uniform base (HW adds lane*16)
__device__ __forceinline__ void gl_lds16(const bf16_t* g, bf16_t* l) {
  __builtin_amdgcn_global_load_lds(
      (const __attribute__((address_space(1))) void*)g,
      (__attribute__((address_space(3))) void*)l, 16, 0, 0);
}

// ---------------- cast f32 -> bf16 (vectorized) ----------------
__global__ __launch_bounds__(256) void k_cast_bf16(const float* __restrict__ in,
                                                   bf16_t* __restrict__ out, int n) {
  int tid = blockIdx.x * blockDim.x + threadIdx.x;
  int stride = gridDim.x * blockDim.x;
  for (int i = tid * 4; i < n; i += stride * 4) {
    float4 a = *(const float4*)(in + i);
    bf16x4_t r = { (bf16_t)a.x, (bf16_t)a.y, (bf16_t)a.z, (bf16_t)a.w };
    *(bf16x4_t*)(out + i) = r;
  }
}

// ---------------- transpose + cast: W[K][N] f32 -> WT[N][K] bf16 ----------------
__global__ __launch_bounds__(256) void k_trans_cast(const float* __restrict__ W,
                                                    bf16_t* __restrict__ WT,
                                                    int K, int N) {
  __shared__ float tile[32][33];
  int n0 = blockIdx.x * 32, k0 = blockIdx.y * 32;
  int tx = threadIdx.x & 31, ty = threadIdx.x >> 5;  // 32 x 8
#pragma unroll
  for (int j = 0; j < 4; j++)
    tile[ty + j * 8][tx] = W[(size_t)(k0 + ty + j * 8) * N + n0 + tx];
  __syncthreads();
#pragma unroll
  for (int j = 0; j < 4; j++)
    WT[(size_t)(n0 + ty + j * 8) * K + k0 + tx] = (bf16_t)tile[tx][ty + j * 8];
}

// ---------------- RoPE cos/sin table [T][32] f32 ----------------
__global__ __launch_bounds__(256) void k_rope_table(float* __restrict__ cs,
                                                    float* __restrict__ sn) {
  int i = blockIdx.x * blockDim.x + threadIdx.x;  // t*32 + j
  if (i >= T_SEQ * 32) return;
  int t = i >> 5, j = i & 31;
  float inv = powf(10000.0f, -(float)(2 * j) / 64.0f);
  float f = (float)t * inv;
  cs[i] = cosf(f);
  sn[i] = sinf(f);
}

// ---------------- GEMM: C[M][N] = A[M][K] * BT[N][K]^T  (bf16 in, OUT out) ----------
// 128x128 tile, BK=32, 256 threads (4 waves, 2x2), each wave 64x64 via 4x4 16x16x32.
template <typename OUT>
__global__ __launch_bounds__(256) void k_gemm_bt(const bf16_t* __restrict__ A,
                                                 const bf16_t* __restrict__ Bt,
                                                 OUT* __restrict__ C,
                                                 int M, int N, int K) {
  __shared__ __align__(16) bf16_t As[128 * 32];
  __shared__ __align__(16) bf16_t Bs[128 * 32];
  int m0 = blockIdx.y * 128, n0 = blockIdx.x * 128;
  int tid = threadIdx.x;
  int lane = tid & 63, w = tid >> 6;
  int wr = w >> 1, wc = w & 1;
  int l15 = lane & 15, l4 = lane >> 4;

  f32x4_t acc[4][4];
#pragma unroll
  for (int m = 0; m < 4; m++)
#pragma unroll
    for (int n = 0; n < 4; n++) acc[m][n] = (f32x4_t){0.f, 0.f, 0.f, 0.f};

  for (int k0 = 0; k0 < K; k0 += 32) {
#pragma unroll
    for (int j = 0; j < 2; j++) {
      int c = j * 256 + tid;          // chunk id, 512 chunks of 16B per tile
      int row = c >> 2, kb = c & 3;   // 4 chunks per 32-elem row
      gl_lds16(A + (size_t)(m0 + row) * K + k0 + kb * 8, As + (size_t)(j * 256 + w * 64) * 8);
      gl_lds16(Bt + (size_t)(n0 + row) * K + k0 + kb * 8, Bs + (size_t)(j * 256 + w * 64) * 8);
    }
    __syncthreads();
    bf16x8_t af[4], bfr[4];
#pragma unroll
    for (int m = 0; m < 4; m++)
      af[m] = *(const bf16x8_t*)(As + (size_t)(wr * 64 + m * 16 + l15) * 32 + l4 * 8);
#pragma unroll
    for (int n = 0; n < 4; n++)
      bfr[n] = *(const bf16x8_t*)(Bs + (size_t)(wc * 64 + n * 16 + l15) * 32 + l4 * 8);
#pragma unroll
    for (int m = 0; m < 4; m++)
#pragma unroll
      for (int n = 0; n < 4; n++) acc[m][n] = mfma16(af[m], bfr[n], acc[m][n]);
    __syncthreads();
  }
#pragma unroll
  for (int m = 0; m < 4; m++)
#pragma unroll
    for (int n = 0; n < 4; n++)
#pragma unroll
      for (int r = 0; r < 4; r++) {
        int row = m0 + wr * 64 + m * 16 + l4 * 4 + r;
        int col = n0 + wc * 64 + n * 16 + l15;
        C[(size_t)row * N + col] = (OUT)acc[m][n][r];
      }
}

// ---------------- RoPE + relayout ----------------
// qkv [BT][3072] bf16 -> Qr,Kr [bh][t][64] (Q scaled by 0.125), Vt [bh][64][t]
__global__ __launch_bounds__(256) void k_rope_layout(const bf16_t* __restrict__ qkv,
                                                     const float* __restrict__ cs,
                                                     const float* __restrict__ sn,
                                                     bf16_t* __restrict__ Qr,
                                                     bf16_t* __restrict__ Kr,
                                                     bf16_t* __restrict__ Vt) {
  int tb = blockIdx.x, bh = blockIdx.y;
  int b = bh >> 4, h = bh & 15;
  int t0 = tb * 64;
  int tid = threadIdx.x;
  int j = tid & 31, tl = tid >> 5;  // j: rot pair, tl: row 0..7

#pragma unroll
  for (int p = 0; p < 8; p++) {
    int t = t0 + p * 8 + tl;
    size_t rowoff = (size_t)(b * T_SEQ + t) * 3072;
    float c = cs[t * 32 + j], s = sn[t * 32 + j];
    size_t qo = ((size_t)bh * T_SEQ + t) * 64;
    // Q (scaled by 1/8 = exact in bf16)
    float x1 = (float)qkv[rowoff + h * 64 + j];
    float x2 = (float)qkv[rowoff + h * 64 + 32 + j];
    Qr[qo + j]      = (bf16_t)((x1 * c - x2 * s) * 0.125f);
    Qr[qo + 32 + j] = (bf16_t)((x1 * s + x2 * c) * 0.125f);
    // K
    x1 = (float)qkv[rowoff + 1024 + h * 64 + j];
    x2 = (float)qkv[rowoff + 1024 + h * 64 + 32 + j];
    Kr[qo + j]      = (bf16_t)(x1 * c - x2 * s);
    Kr[qo + 32 + j] = (bf16_t)(x1 * s + x2 * c);
  }

  // V: [t][dh] -> Vt[bh][dh][t] via LDS tile
  __shared__ bf16_t vt[64][65];
#pragma unroll
  for (int p = 0; p < 16; p++) {
    int idx = p * 256 + tid;
    int tl2 = idx >> 6, d = idx & 63;
    vt[d][tl2] = qkv[(size_t)(b * T_SEQ + t0 + tl2) * 3072 + 2048 + h * 64 + d];
  }
  __syncthreads();
#pragma unroll
  for (int p = 0; p < 16; p++) {
    int idx = p * 256 + tid;
    int d = idx >> 6, tl2 = idx & 63;
    Vt[((size_t)bh * 64 + d) * T_SEQ + t0 + tl2] = vt[d][tl2];
  }
}

// ---------------- flash attention ----------------
// grid: (T/64, B*H). 4 waves, each 16 q-rows. KV tiles of 64. Causal.
// Swapped QK^T (S^T in regs, q = lane&15), in-register softmax, P via 72-stride LDS,
// 2-phase double-buffered gl_lds staging with XOR-swizzled K/V tiles.
__global__ __launch_bounds__(256) void k_attn(const bf16_t* __restrict__ Qr,
                                              const bf16_t* __restrict__ Kr,
                                              const bf16_t* __restrict__ Vt,
                                              bf16_t* __restrict__ Ob) {
  __shared__ __align__(16) bf16_t Ks[2][64 * 64];
  __shared__ __align__(16) bf16_t Vs[2][64 * 64];
  __shared__ __align__(16) bf16_t Ps[64 * 72];  // stride 72 (144B = 16B*9): conflict-free b128
  int qb = blockIdx.x, bh = blockIdx.y;
  int b = bh >> 4, h = bh & 15;
  int q0 = qb * 64;
  int tid = threadIdx.x, lane = tid & 63, w = tid >> 6;
  int l15 = lane & 15, l4 = lane >> 4;

  // Q fragments (B-operand for swapped QK^T): col=q=l15, k=l4*8+i
  bf16x8_t qf[2];
  size_t qbase = ((size_t)bh * T_SEQ + q0 + w * 16 + l15) * 64;
  qf[0] = *(const bf16x8_t*)(Qr + qbase + l4 * 8);
  qf[1] = *(const bf16x8_t*)(Qr + qbase + 32 + l4 * 8);

  f32x4_t o[4];
#pragma unroll
  for (int n = 0; n < 4; n++) o[n] = (f32x4_t){0.f, 0.f, 0.f, 0.f};
  float m_s = -1e30f, l_s = 0.f;  // running max/sum for q = q0 + w*16 + l15 (x4 replicated)

  const bf16_t* Kbh = Kr + (size_t)bh * T_SEQ * 64;
  const bf16_t* Vbh = Vt + (size_t)bh * 64 * T_SEQ;

  // stage K/V tile `it` into buffer `buf`; global chunk index pre-swizzled (k8 ^= row&7)
  // so linear gl_lds dest == swizzled layout (both-sides rule).
  auto stage = [&](int buf, int it) {
    int kb = it * 64;
#pragma unroll
    for (int j = 0; j < 2; j++) {
      int c = j * 256 + tid;
      int row = c >> 3, k8 = c & 7;
      int sk8 = k8 ^ (row & 7);
      gl_lds16(Kbh + (size_t)(kb + row) * 64 + sk8 * 8, Ks[buf] + (size_t)(j * 256 + w * 64) * 8);
      gl_lds16(Vbh + (size_t)row * T_SEQ + kb + sk8 * 8, Vs[buf] + (size_t)(j * 256 + w * 64) * 8);
    }
  };

  int nit = qb + 1;
  stage(0, 0);
  asm volatile("s_waitcnt vmcnt(0)" ::: "memory");
  __builtin_amdgcn_s_barrier();

  for (int it = 0; it < nit; it++) {
    int cur = it & 1;
    if (it + 1 < nit) stage(cur ^ 1, it + 1);  // prefetch next tile (overlaps compute)

    // S^T = K Q^T : D[kv_local = l4*4+r (+16n)][q_local = l15]
    f32x4_t s[4];
#pragma unroll
    for (int n = 0; n < 4; n++) {
      int rowK = n * 16 + l15;
      const bf16_t* kp = Ks[cur] + (size_t)rowK * 64;
      int sw = rowK & 7;
      bf16x8_t kf0 = *(const bf16x8_t*)(kp + (l4 ^ sw) * 8);
      bf16x8_t kf1 = *(const bf16x8_t*)(kp + ((l4 ^ 4) ^ sw) * 8);
      s[n] = (f32x4_t){0.f, 0.f, 0.f, 0.f};
      s[n] = mfma16(kf0, qf[0], s[n]);
      s[n] = mfma16(kf1, qf[1], s[n]);
    }

    if (it == qb) {  // diagonal tile: causal mask (kb == q0)
#pragma unroll
      for (int n = 0; n < 4; n++)
#pragma unroll
        for (int r = 0; r < 4; r++)
          if (n * 16 + l4 * 4 + r > w * 16 + l15) s[n][r] = -1e30f;
    }

    // online softmax: 16 vals in-lane (one q-row) + reduce across l4 groups (2 shfl)
    float t0 = fmaxf(fmaxf(s[0][0], s[0][1]), fmaxf(s[0][2], s[0][3]));
    float t1 = fmaxf(fmaxf(s[1][0], s[1][1]), fmaxf(s[1][2], s[1][3]));
    float t2 = fmaxf(fmaxf(s[2][0], s[2][1]), fmaxf(s[2][2], s[2][3]));
    float t3 = fmaxf(fmaxf(s[3][0], s[3][1]), fmaxf(s[3][2], s[3][3]));
    float mx = fmaxf(fmaxf(t0, t1), fmaxf(t2, t3));
    mx = fmaxf(mx, __shfl_xor(mx, 16, 64));
    mx = fmaxf(mx, __shfl_xor(mx, 32, 64));
    float mnew = fmaxf(m_s, mx);
    float alpha = __expf(m_s - mnew);
    m_s = mnew;

    float sum = 0.f;
#pragma unroll
    for (int n = 0; n < 4; n++) {
#pragma unroll
      for (int r = 0; r < 4; r++) s[n][r] = __expf(s[n][r] - mnew);
      bf16x4_t pk = { (bf16_t)s[n][0], (bf16_t)s[n][1], (bf16_t)s[n][2], (bf16_t)s[n][3] };
      *(bf16x4_t*)(Ps + (size_t)(w * 16 + l15) * 72 + n * 16 + l4 * 4) = pk;
      sum += (s[n][0] + s[n][1]) + (s[n][2] + s[n][3]);
    }
    sum += __shfl_xor(sum, 16, 64);
    sum += __shfl_xor(sum, 32, 64);
    l_s = l_s * alpha + sum;

    // rescale O: alpha for my accumulator rows (q_local = l4*4+r) via bpermute
    float ar[4];
#pragma unroll
    for (int r = 0; r < 4; r++) ar[r] = __shfl(alpha, l4 * 4 + r, 64);
#pragma unroll
    for (int n = 0; n < 4; n++)
#pragma unroll
      for (int r = 0; r < 4; r++) o[n][r] *= ar[r];

    // O += P V  (A = P[q][kv] from Ps, B = V[kv][d] from swizzled Vs[d][kv])
#pragma unroll
    for (int ks = 0; ks < 2; ks++) {
      bf16x8_t pa = *(const bf16x8_t*)(Ps + (size_t)(w * 16 + l15) * 72 + ks * 32 + l4 * 8);
#pragma unroll
      for (int n = 0; n < 4; n++) {
        int rowV = n * 16 + l15;
        bf16x8_t vf = *(const bf16x8_t*)(Vs[cur] + (size_t)rowV * 64 +
                                         (((ks * 4 + l4) ^ (rowV & 7)) * 8));
        o[n] = mfma16(pa, vf, o[n]);
      }
    }

    // drain my prefetch-issues and LDS ops, then single barrier per iter
    asm volatile("s_waitcnt vmcnt(0) lgkmcnt(0)" ::: "memory");
    __builtin_amdgcn_s_barrier();
  }

  // epilogue: Ob[b*T+q][h*64+d] = O / l  (l for q_local=l4*4+r via bpermute)
  float linv = 1.0f / l_s;
#pragma unroll
  for (int r = 0; r < 4; r++) {
    float ir = __shfl(linv, l4 * 4 + r, 64);
    int q = q0 + w * 16 + l4 * 4 + r;
    size_t off = ((size_t)(b * T_SEQ + q)) * 1024 + h * 64;
#pragma unroll
    for (int n = 0; n < 4; n++)
      Ob[off + n * 16 + l15] = (bf16_t)(o[n][r] * ir);
  }
}

// ---------------- launch ----------------
extern "C" void kernel_launch(void* const* d_in, const int* in_sizes, int n_in,
                              void* d_out, int out_size, void* d_ws, size_t ws_size,
                              hipStream_t stream) {
  const float* x    = (const float*)d_in[0];
  const float* Wqkv = (const float*)d_in[1];
  const float* Wout = (const float*)d_in[2];
  float* out = (float*)d_out;
  char* ws = (char*)d_ws;

  // ws layout (bytes); total ~64.5 MB
  bf16_t* wqkvT = (bf16_t*)(ws + 0);                       // [3072][1024] 6 MB
  bf16_t* woutT = (bf16_t*)(ws + 6291456);                 // [1024][1024] 2 MB
  bf16_t* xb    = (bf16_t*)(ws + 8388608);                 // [4096][1024] 8 MB (reused as Ob)
  bf16_t* qkv   = (bf16_t*)(ws + 16777216);                // [4096][3072] 24 MB
  bf16_t* Qr    = (bf16_t*)(ws + 41943040);                // [32][2048][64] 8 MB
  bf16_t* Kr    = (bf16_t*)(ws + 50331648);                // 8 MB
  bf16_t* Vt    = (bf16_t*)(ws + 58720256);                // [32][64][2048] 8 MB
  float*  cs    = (float*)(ws + 67108864);                 // [2048][32] 256 KB
  float*  sn    = (float*)(ws + 67371008);                 // 256 KB
  bf16_t* Ob    = xb;  // xb dead after GEMM1

  k_cast_bf16<<<2048, 256, 0, stream>>>(x, xb, 4096 * 1024);
  k_trans_cast<<<dim3(3072 / 32, 1024 / 32), 256, 0, stream>>>(Wqkv, wqkvT, 1024, 3072);
  k_trans_cast<<<dim3(1024 / 32, 1024 / 32), 256, 0, stream>>>(Wout, woutT, 1024, 1024);
  k_rope_table<<<(T_SEQ * 32) / 256, 256, 0, stream>>>(cs, sn);

  k_gemm_bt<bf16_t><<<dim3(3072 / 128, 4096 / 128), 256, 0, stream>>>(xb, wqkvT, qkv,
                                                                      4096, 3072, 1024);
  k_rope_layout<<<dim3(T_SEQ / 64, NBH), 256, 0, stream>>>(qkv, cs, sn, Qr, Kr, Vt);
  k_attn<<<dim3(T_SEQ / 64, NBH), 256, 0, stream>>>(Qr, Kr, Vt, Ob);
  k_gemm_bt<float><<<dim3(1024 / 128, 4096 / 128), 256, 0, stream>>>(Ob, woutT, out,
                                                                     4096, 1024, 1024);
}

// Round 3
// 128.823 us; speedup vs baseline: 1.8122x; 1.3594x over previous
//
#include <hip/hip_runtime.h>
#include <hip/hip_bf16.h>
#include <stdint.h>
#include <math.h>

// B=2, T=2048, D=1024, H=16, DH=64
#define T_SEQ 2048
#define NHEAD 16
#define NBH   32      // B*H
#define BTROW 4096    // B*T

typedef __bf16 bf16_t;
typedef __bf16 bf16x4_t __attribute__((ext_vector_type(4)));
typedef __bf16 bf16x8_t __attribute__((ext_vector_type(8)));
typedef float  f32x4_t  __attribute__((ext_vector_type(4)));

// 0.125 (1/sqrt(64)) * log2(e) — folded into Q so softmax uses exp2 directly
#define QSCALE 0.18033688011112042f

__device__ __forceinline__ f32x4_t mfma16(bf16x8_t a, bf16x8_t b, f32x4_t c) {
  return __builtin_amdgcn_mfma_f32_16x16x32_bf16(a, b, c, 0, 0, 0);
}

__device__ __forceinline__ float fast_exp2(float x) {
#if __has_builtin(__builtin_amdgcn_exp2f)
  return __builtin_amdgcn_exp2f(x);
#else
  return exp2f(x);
#endif
}

// async global->LDS, 16B per lane; lds dest is wave-uniform base (HW adds lane*16)
__device__ __forceinline__ void gl_lds16(const bf16_t* g, bf16_t* l) {
  __builtin_amdgcn_global_load_lds(
      (const __attribute__((address_space(1))) void*)g,
      (__attribute__((address_space(3))) void*)l, 16, 0, 0);
}

// ---------------- cast f32 -> bf16 (vectorized) ----------------
__global__ __launch_bounds__(256) void k_cast_bf16(const float* __restrict__ in,
                                                   bf16_t* __restrict__ out, int n) {
  int tid = blockIdx.x * blockDim.x + threadIdx.x;
  int stride = gridDim.x * blockDim.x;
  for (int i = tid * 4; i < n; i += stride * 4) {
    float4 a = *(const float4*)(in + i);
    bf16x4_t r = { (bf16_t)a.x, (bf16_t)a.y, (bf16_t)a.z, (bf16_t)a.w };
    *(bf16x4_t*)(out + i) = r;
  }
}

// ---------------- transpose + cast: W[K][N] f32 -> WT[N][K] bf16 ----------------
__global__ __launch_bounds__(256) void k_trans_cast(const float* __restrict__ W,
                                                    bf16_t* __restrict__ WT,
                                                    int K, int N) {
  __shared__ float tile[32][33];
  int n0 = blockIdx.x * 32, k0 = blockIdx.y * 32;
  int tx = threadIdx.x & 31, ty = threadIdx.x >> 5;  // 32 x 8
#pragma unroll
  for (int j = 0; j < 4; j++)
    tile[ty + j * 8][tx] = W[(size_t)(k0 + ty + j * 8) * N + n0 + tx];
  __syncthreads();
#pragma unroll
  for (int j = 0; j < 4; j++)
    WT[(size_t)(n0 + ty + j * 8) * K + k0 + tx] = (bf16_t)tile[tx][ty + j * 8];
}

// ---------------- RoPE cos/sin table [T][32] f32 ----------------
__global__ __launch_bounds__(256) void k_rope_table(float* __restrict__ cs,
                                                    float* __restrict__ sn) {
  int i = blockIdx.x * blockDim.x + threadIdx.x;  // t*32 + j
  if (i >= T_SEQ * 32) return;
  int t = i >> 5, j = i & 31;
  float inv = powf(10000.0f, -(float)(2 * j) / 64.0f);
  float f = (float)t * inv;
  cs[i] = cosf(f);
  sn[i] = sinf(f);
}

// ---------------- GEMM: C[M][N] = A[M][K] * BT[N][K]^T  (bf16 in, OUT out) ----------
// 128x128 tile, BK=32, 256 threads (4 waves, 2x2), each wave 64x64 via 4x4 16x16x32.
template <typename OUT>
__global__ __launch_bounds__(256) void k_gemm_bt(const bf16_t* __restrict__ A,
                                                 const bf16_t* __restrict__ Bt,
                                                 OUT* __restrict__ C,
                                                 int M, int N, int K) {
  __shared__ __align__(16) bf16_t As[128 * 32];
  __shared__ __align__(16) bf16_t Bs[128 * 32];
  int m0 = blockIdx.y * 128, n0 = blockIdx.x * 128;
  int tid = threadIdx.x;
  int lane = tid & 63, w = tid >> 6;
  int wr = w >> 1, wc = w & 1;
  int l15 = lane & 15, l4 = lane >> 4;

  f32x4_t acc[4][4];
#pragma unroll
  for (int m = 0; m < 4; m++)
#pragma unroll
    for (int n = 0; n < 4; n++) acc[m][n] = (f32x4_t){0.f, 0.f, 0.f, 0.f};

  for (int k0 = 0; k0 < K; k0 += 32) {
#pragma unroll
    for (int j = 0; j < 2; j++) {
      int c = j * 256 + tid;          // chunk id, 512 chunks of 16B per tile
      int row = c >> 2, kb = c & 3;   // 4 chunks per 32-elem row
      gl_lds16(A + (size_t)(m0 + row) * K + k0 + kb * 8, As + (size_t)(j * 256 + w * 64) * 8);
      gl_lds16(Bt + (size_t)(n0 + row) * K + k0 + kb * 8, Bs + (size_t)(j * 256 + w * 64) * 8);
    }
    __syncthreads();
    bf16x8_t af[4], bfr[4];
#pragma unroll
    for (int m = 0; m < 4; m++)
      af[m] = *(const bf16x8_t*)(As + (size_t)(wr * 64 + m * 16 + l15) * 32 + l4 * 8);
#pragma unroll
    for (int n = 0; n < 4; n++)
      bfr[n] = *(const bf16x8_t*)(Bs + (size_t)(wc * 64 + n * 16 + l15) * 32 + l4 * 8);
#pragma unroll
    for (int m = 0; m < 4; m++)
#pragma unroll
      for (int n = 0; n < 4; n++) acc[m][n] = mfma16(af[m], bfr[n], acc[m][n]);
    __syncthreads();
  }
#pragma unroll
  for (int m = 0; m < 4; m++)
#pragma unroll
    for (int n = 0; n < 4; n++)
#pragma unroll
      for (int r = 0; r < 4; r++) {
        int row = m0 + wr * 64 + m * 16 + l4 * 4 + r;
        int col = n0 + wc * 64 + n * 16 + l15;
        C[(size_t)row * N + col] = (OUT)acc[m][n][r];
      }
}

// ---------------- fused QKV GEMM + RoPE + V-transpose ----------------
// C = xb[4096][1024] @ wqkvT^T -> per-region epilogue:
//   cols 0..1023   (Q): rope, * QSCALE, -> Qr[bh][t][64]
//   cols 1024..2047(K): rope           -> Kr[bh][t][64]
//   cols 2048..3071(V): transpose      -> Vt[bh][64][t]
__global__ __launch_bounds__(256) void k_gemm_qkv(const bf16_t* __restrict__ A,
                                                  const bf16_t* __restrict__ Bt,
                                                  const float* __restrict__ cs,
                                                  const float* __restrict__ sn,
                                                  bf16_t* __restrict__ Qr,
                                                  bf16_t* __restrict__ Kr,
                                                  bf16_t* __restrict__ Vt) {
  const int M = 4096, N = 3072, K = 1024;
  // As(8KB) + Bs(8KB) live during the K loop; vtile(33792B) reuses the same
  // region after the loop's final barrier (V blocks only).
  __shared__ __align__(16) unsigned char smem[128 * 132 * 2];
  bf16_t* As = (bf16_t*)smem;
  bf16_t* Bs = (bf16_t*)(smem + 8192);
  bf16_t* vtile = (bf16_t*)smem;

  int m0 = blockIdx.y * 128, n0 = blockIdx.x * 128;
  int tid = threadIdx.x;
  int lane = tid & 63, w = tid >> 6;
  int wr = w >> 1, wc = w & 1;
  int l15 = lane & 15, l4 = lane >> 4;

  f32x4_t acc[4][4];
#pragma unroll
  for (int m = 0; m < 4; m++)
#pragma unroll
    for (int n = 0; n < 4; n++) acc[m][n] = (f32x4_t){0.f, 0.f, 0.f, 0.f};

  for (int k0 = 0; k0 < K; k0 += 32) {
#pragma unroll
    for (int j = 0; j < 2; j++) {
      int c = j * 256 + tid;
      int row = c >> 2, kb = c & 3;
      gl_lds16(A + (size_t)(m0 + row) * K + k0 + kb * 8, As + (size_t)(j * 256 + w * 64) * 8);
      gl_lds16(Bt + (size_t)(n0 + row) * K + k0 + kb * 8, Bs + (size_t)(j * 256 + w * 64) * 8);
    }
    __syncthreads();
    bf16x8_t af[4], bfr[4];
#pragma unroll
    for (int m = 0; m < 4; m++)
      af[m] = *(const bf16x8_t*)(As + (size_t)(wr * 64 + m * 16 + l15) * 32 + l4 * 8);
#pragma unroll
    for (int n = 0; n < 4; n++)
      bfr[n] = *(const bf16x8_t*)(Bs + (size_t)(wc * 64 + n * 16 + l15) * 32 + l4 * 8);
#pragma unroll
    for (int m = 0; m < 4; m++)
#pragma unroll
      for (int n = 0; n < 4; n++) acc[m][n] = mfma16(af[m], bfr[n], acc[m][n]);
    __syncthreads();
  }

  int region = n0 >> 10;  // 0=Q, 1=K, 2=V (region boundaries are 128-aligned)
  if (region < 2) {
    bf16_t* dst = region ? Kr : Qr;
    float qs = region ? 1.0f : QSCALE;
    int h = ((n0 & 1023) + wc * 64) >> 6;  // wave covers exactly one head
#pragma unroll
    for (int m = 0; m < 4; m++)
#pragma unroll
      for (int r = 0; r < 4; r++) {
        int row = m0 + wr * 64 + m * 16 + l4 * 4 + r;
        int b = row >> 11, t = row & 2047;
        size_t obase = ((size_t)(b * NHEAD + h) * T_SEQ + t) * 64;
#pragma unroll
        for (int n = 0; n < 2; n++) {
          int j = n * 16 + l15;
          float c = cs[t * 32 + j], s = sn[t * 32 + j];
          float x1 = acc[m][n][r], x2 = acc[m][n + 2][r];
          dst[obase + j]      = (bf16_t)((x1 * c - x2 * s) * qs);
          dst[obase + 32 + j] = (bf16_t)((x1 * s + x2 * c) * qs);
        }
      }
  } else {
    // V: stage C-tile into LDS transposed, then coalesced store to Vt[bh][d][t]
#pragma unroll
    for (int m = 0; m < 4; m++)
#pragma unroll
      for (int n = 0; n < 4; n++)
#pragma unroll
        for (int r = 0; r < 4; r++)
          vtile[(size_t)(wc * 64 + n * 16 + l15) * 132 + wr * 64 + m * 16 + l4 * 4 + r] =
              (bf16_t)acc[m][n][r];
    __syncthreads();
    int colbase = n0 - 2048;
    int b = m0 >> 11, t0l = m0 & 2047;
#pragma unroll
    for (int p = 0; p < 64; p++) {
      int idx = p * 256 + tid;       // 128x128 elems / 256 threads
      int dl = idx >> 7, tl = idx & 127;
      int col = colbase + dl, h = col >> 6, d = col & 63;
      Vt[((size_t)(b * NHEAD + h) * 64 + d) * T_SEQ + t0l + tl] = vtile[(size_t)dl * 132 + tl];
    }
  }
}

// ---------------- flash attention ----------------
// grid: (16, B*H). Block processes q-tiles p and 31-p sequentially -> exactly 33
// KV-tile iters per block, 512 blocks = 2/CU (perfect balance, cross-block overlap).
// Swapped QK^T (S^T in regs, q = lane&15), in-register softmax (exp2 domain,
// scale pre-folded into Q), defer-max (THR=8), P via 72-stride LDS,
// 2-phase double-buffered gl_lds staging with XOR-swizzled K/V tiles.
__global__ __launch_bounds__(256) void k_attn(const bf16_t* __restrict__ Qr,
                                              const bf16_t* __restrict__ Kr,
                                              const bf16_t* __restrict__ Vt,
                                              bf16_t* __restrict__ Ob) {
  __shared__ __align__(16) bf16_t Ks[2][64 * 64];
  __shared__ __align__(16) bf16_t Vs[2][64 * 64];
  __shared__ __align__(16) bf16_t Ps[64 * 72];  // stride 72: conflict-free b128
  int pidx = blockIdx.x, bh = blockIdx.y;
  int b = bh >> 4, h = bh & 15;
  int tid = threadIdx.x, lane = tid & 63, w = tid >> 6;
  int l15 = lane & 15, l4 = lane >> 4;

  const bf16_t* Kbh = Kr + (size_t)bh * T_SEQ * 64;
  const bf16_t* Vbh = Vt + (size_t)bh * 64 * T_SEQ;

  auto stage = [&](int buf, int it) {
    int kb = it * 64;
#pragma unroll
    for (int j = 0; j < 2; j++) {
      int c = j * 256 + tid;
      int row = c >> 3, k8 = c & 7;
      int sk8 = k8 ^ (row & 7);  // pre-swizzled source <-> swizzled read (both-sides rule)
      gl_lds16(Kbh + (size_t)(kb + row) * 64 + sk8 * 8, Ks[buf] + (size_t)(j * 256 + w * 64) * 8);
      gl_lds16(Vbh + (size_t)row * T_SEQ + kb + sk8 * 8, Vs[buf] + (size_t)(j * 256 + w * 64) * 8);
    }
  };

  for (int pass = 0; pass < 2; pass++) {
    int qb = pass ? (31 - pidx) : pidx;
    int q0 = qb * 64;
    int nit = qb + 1;

    // Q fragments (B-operand for swapped QK^T): col=q=l15, k=l4*8+i
    bf16x8_t qf[2];
    size_t qbase = ((size_t)bh * T_SEQ + q0 + w * 16 + l15) * 64;
    qf[0] = *(const bf16x8_t*)(Qr + qbase + l4 * 8);
    qf[1] = *(const bf16x8_t*)(Qr + qbase + 32 + l4 * 8);

    f32x4_t o[4];
#pragma unroll
    for (int n = 0; n < 4; n++) o[n] = (f32x4_t){0.f, 0.f, 0.f, 0.f};
    float m_s = -1e30f, l_s = 0.f;

    stage(0, 0);
    asm volatile("s_waitcnt vmcnt(0)" ::: "memory");
    __builtin_amdgcn_s_barrier();

    for (int it = 0; it < nit; it++) {
      int cur = it & 1;
      if (it + 1 < nit) stage(cur ^ 1, it + 1);  // prefetch next tile under compute

      // S^T = K Q^T : D[kv_local = l4*4+r (+16n)][q = l15]
      f32x4_t s[4];
      __builtin_amdgcn_s_setprio(1);
#pragma unroll
      for (int n = 0; n < 4; n++) {
        int rowK = n * 16 + l15;
        const bf16_t* kp = Ks[cur] + (size_t)rowK * 64;
        int sw = rowK & 7;
        bf16x8_t kf0 = *(const bf16x8_t*)(kp + (l4 ^ sw) * 8);
        bf16x8_t kf1 = *(const bf16x8_t*)(kp + ((l4 ^ 4) ^ sw) * 8);
        s[n] = (f32x4_t){0.f, 0.f, 0.f, 0.f};
        s[n] = mfma16(kf0, qf[0], s[n]);
        s[n] = mfma16(kf1, qf[1], s[n]);
      }
      __builtin_amdgcn_s_setprio(0);

      if (it == qb) {  // diagonal tile: causal mask
#pragma unroll
        for (int n = 0; n < 4; n++)
#pragma unroll
          for (int r = 0; r < 4; r++)
            if (n * 16 + l4 * 4 + r > w * 16 + l15) s[n][r] = -1e30f;
      }

      // row max: 16 in-lane + 2 shfl (row = q = l15, replicated over l4 groups)
      float t0 = fmaxf(fmaxf(s[0][0], s[0][1]), fmaxf(s[0][2], s[0][3]));
      float t1 = fmaxf(fmaxf(s[1][0], s[1][1]), fmaxf(s[1][2], s[1][3]));
      float t2 = fmaxf(fmaxf(s[2][0], s[2][1]), fmaxf(s[2][2], s[2][3]));
      float t3 = fmaxf(fmaxf(s[3][0], s[3][1]), fmaxf(s[3][2], s[3][3]));
      float mx = fmaxf(fmaxf(t0, t1), fmaxf(t2, t3));
      mx = fmaxf(mx, __shfl_xor(mx, 16, 64));
      mx = fmaxf(mx, __shfl_xor(mx, 32, 64));

      // defer-max (T13): only rescale when the running max grew by > 8 (exp2 domain)
      if (__any(mx - m_s > 8.0f)) {
        float mnew = fmaxf(m_s, mx);
        float alpha = fast_exp2(m_s - mnew);
        m_s = mnew;
        l_s *= alpha;
        float ar[4];
#pragma unroll
        for (int r = 0; r < 4; r++) ar[r] = __shfl(alpha, l4 * 4 + r, 64);
#pragma unroll
        for (int n = 0; n < 4; n++)
#pragma unroll
          for (int r = 0; r < 4; r++) o[n][r] *= ar[r];
      }

      float sum = 0.f;
#pragma unroll
      for (int n = 0; n < 4; n++) {
#pragma unroll
        for (int r = 0; r < 4; r++) s[n][r] = fast_exp2(s[n][r] - m_s);
        bf16x4_t pk = { (bf16_t)s[n][0], (bf16_t)s[n][1], (bf16_t)s[n][2], (bf16_t)s[n][3] };
        *(bf16x4_t*)(Ps + (size_t)(w * 16 + l15) * 72 + n * 16 + l4 * 4) = pk;
        sum += (s[n][0] + s[n][1]) + (s[n][2] + s[n][3]);
      }
      sum += __shfl_xor(sum, 16, 64);
      sum += __shfl_xor(sum, 32, 64);
      l_s += sum;

      // O += P V  (A = P[q][kv] from Ps, B = V[kv][d] from swizzled Vs[d][kv])
      __builtin_amdgcn_s_setprio(1);
#pragma unroll
      for (int ks = 0; ks < 2; ks++) {
        bf16x8_t pa = *(const bf16x8_t*)(Ps + (size_t)(w * 16 + l15) * 72 + ks * 32 + l4 * 8);
#pragma unroll
        for (int n = 0; n < 4; n++) {
          int rowV = n * 16 + l15;
          bf16x8_t vf = *(const bf16x8_t*)(Vs[cur] + (size_t)rowV * 64 +
                                           (((ks * 4 + l4) ^ (rowV & 7)) * 8));
          o[n] = mfma16(pa, vf, o[n]);
        }
      }
      __builtin_amdgcn_s_setprio(0);

      asm volatile("s_waitcnt vmcnt(0) lgkmcnt(0)" ::: "memory");
      __builtin_amdgcn_s_barrier();
    }

    // epilogue: Ob[b*T+q][h*64+d] = O / l
    float linv = 1.0f / l_s;
#pragma unroll
    for (int r = 0; r < 4; r++) {
      float ir = __shfl(linv, l4 * 4 + r, 64);
      int q = q0 + w * 16 + l4 * 4 + r;
      size_t off = ((size_t)(b * T_SEQ + q)) * 1024 + h * 64;
#pragma unroll
      for (int n = 0; n < 4; n++)
        Ob[off + n * 16 + l15] = (bf16_t)(o[n][r] * ir);
    }
  }
}

// ---------------- launch ----------------
extern "C" void kernel_launch(void* const* d_in, const int* in_sizes, int n_in,
                              void* d_out, int out_size, void* d_ws, size_t ws_size,
                              hipStream_t stream) {
  const float* x    = (const float*)d_in[0];
  const float* Wqkv = (const float*)d_in[1];
  const float* Wout = (const float*)d_in[2];
  float* out = (float*)d_out;
  char* ws = (char*)d_ws;

  bf16_t* wqkvT = (bf16_t*)(ws + 0);                       // [3072][1024] 6 MB
  bf16_t* woutT = (bf16_t*)(ws + 6291456);                 // [1024][1024] 2 MB
  bf16_t* xb    = (bf16_t*)(ws + 8388608);                 // [4096][1024] 8 MB (reused as Ob)
  bf16_t* Qr    = (bf16_t*)(ws + 41943040);                // [32][2048][64] 8 MB
  bf16_t* Kr    = (bf16_t*)(ws + 50331648);                // 8 MB
  bf16_t* Vt    = (bf16_t*)(ws + 58720256);                // [32][64][2048] 8 MB
  float*  cs    = (float*)(ws + 67108864);                 // [2048][32] 256 KB
  float*  sn    = (float*)(ws + 67371008);                 // 256 KB
  bf16_t* Ob    = xb;  // xb dead after GEMM1

  k_cast_bf16<<<2048, 256, 0, stream>>>(x, xb, 4096 * 1024);
  k_trans_cast<<<dim3(3072 / 32, 1024 / 32), 256, 0, stream>>>(Wqkv, wqkvT, 1024, 3072);
  k_trans_cast<<<dim3(1024 / 32, 1024 / 32), 256, 0, stream>>>(Wout, woutT, 1024, 1024);
  k_rope_table<<<(T_SEQ * 32) / 256, 256, 0, stream>>>(cs, sn);

  k_gemm_qkv<<<dim3(3072 / 128, 4096 / 128), 256, 0, stream>>>(xb, wqkvT, cs, sn, Qr, Kr, Vt);
  k_attn<<<dim3(16, NBH), 256, 0, stream>>>(Qr, Kr, Vt, Ob);
  k_gemm_bt<float><<<dim3(1024 / 128, 4096 / 128), 256, 0, stream>>>(Ob, woutT, out,
                                                                     4096, 1024, 1024);
}

// Round 4
// 118.960 us; speedup vs baseline: 1.9624x; 1.0829x over previous
//
#include <hip/hip_runtime.h>
#include <hip/hip_bf16.h>
#include <stdint.h>
#include <math.h>

// B=2, T=2048, D=1024, H=16, DH=64
#define T_SEQ 2048
#define NHEAD 16
#define NBH   32      // B*H
#define BTROW 4096    // B*T

typedef __bf16 bf16_t;
typedef __bf16 bf16x4_t __attribute__((ext_vector_type(4)));
typedef __bf16 bf16x8_t __attribute__((ext_vector_type(8)));
typedef float  f32x4_t  __attribute__((ext_vector_type(4)));

// 0.125 (1/sqrt(64)) * log2(e) — folded into Q so softmax uses exp2 directly
#define QSCALE 0.18033688011112042f

__device__ __forceinline__ f32x4_t mfma16(bf16x8_t a, bf16x8_t b, f32x4_t c) {
  return __builtin_amdgcn_mfma_f32_16x16x32_bf16(a, b, c, 0, 0, 0);
}

__device__ __forceinline__ float fast_exp2(float x) {
#if __has_builtin(__builtin_amdgcn_exp2f)
  return __builtin_amdgcn_exp2f(x);
#else
  return exp2f(x);
#endif
}

// async global->LDS, 16B per lane; lds dest is wave-uniform base (HW adds lane*16)
__device__ __forceinline__ void gl_lds16(const bf16_t* g, bf16_t* l) {
  __builtin_amdgcn_global_load_lds(
      (const __attribute__((address_space(1))) void*)g,
      (__attribute__((address_space(3))) void*)l, 16, 0, 0);
}

// ---------------- cast f32 -> bf16 (vectorized) ----------------
__global__ __launch_bounds__(256) void k_cast_bf16(const float* __restrict__ in,
                                                   bf16_t* __restrict__ out, int n) {
  int tid = blockIdx.x * blockDim.x + threadIdx.x;
  int stride = gridDim.x * blockDim.x;
  for (int i = tid * 4; i < n; i += stride * 4) {
    float4 a = *(const float4*)(in + i);
    bf16x4_t r = { (bf16_t)a.x, (bf16_t)a.y, (bf16_t)a.z, (bf16_t)a.w };
    *(bf16x4_t*)(out + i) = r;
  }
}

// ---------------- transpose + cast: W[K][N] f32 -> WT[N][K] bf16 ----------------
__global__ __launch_bounds__(256) void k_trans_cast(const float* __restrict__ W,
                                                    bf16_t* __restrict__ WT,
                                                    int K, int N) {
  __shared__ float tile[32][33];
  int n0 = blockIdx.x * 32, k0 = blockIdx.y * 32;
  int tx = threadIdx.x & 31, ty = threadIdx.x >> 5;  // 32 x 8
#pragma unroll
  for (int j = 0; j < 4; j++)
    tile[ty + j * 8][tx] = W[(size_t)(k0 + ty + j * 8) * N + n0 + tx];
  __syncthreads();
#pragma unroll
  for (int j = 0; j < 4; j++)
    WT[(size_t)(n0 + ty + j * 8) * K + k0 + tx] = (bf16_t)tile[tx][ty + j * 8];
}

// ---------------- RoPE cos/sin table [T][32] f32 ----------------
__global__ __launch_bounds__(256) void k_rope_table(float* __restrict__ cs,
                                                    float* __restrict__ sn) {
  int i = blockIdx.x * blockDim.x + threadIdx.x;  // t*32 + j
  if (i >= T_SEQ * 32) return;
  int t = i >> 5, j = i & 31;
  float inv = powf(10000.0f, -(float)(2 * j) / 64.0f);
  float f = (float)t * inv;
  cs[i] = cosf(f);
  sn[i] = sinf(f);
}

// ---------------- fused QKV GEMM + RoPE + V-transpose ----------------
// C = xb[4096][1024] @ wqkvT^T -> per-region epilogue:
//   cols 0..1023   (Q): rope, * QSCALE, -> Qr[bh][t][64]
//   cols 1024..2047(K): rope           -> Kr[bh][t][64]
//   cols 2048..3071(V): transpose      -> Vt[bh][64][t]
__global__ __launch_bounds__(256) void k_gemm_qkv(const bf16_t* __restrict__ A,
                                                  const bf16_t* __restrict__ Bt,
                                                  const float* __restrict__ cs,
                                                  const float* __restrict__ sn,
                                                  bf16_t* __restrict__ Qr,
                                                  bf16_t* __restrict__ Kr,
                                                  bf16_t* __restrict__ Vt) {
  const int K = 1024;
  __shared__ __align__(16) unsigned char smem[128 * 132 * 2];
  bf16_t* As = (bf16_t*)smem;
  bf16_t* Bs = (bf16_t*)(smem + 8192);
  bf16_t* vtile = (bf16_t*)smem;

  int m0 = blockIdx.y * 128, n0 = blockIdx.x * 128;
  int tid = threadIdx.x;
  int lane = tid & 63, w = tid >> 6;
  int wr = w >> 1, wc = w & 1;
  int l15 = lane & 15, l4 = lane >> 4;

  f32x4_t acc[4][4];
#pragma unroll
  for (int m = 0; m < 4; m++)
#pragma unroll
    for (int n = 0; n < 4; n++) acc[m][n] = (f32x4_t){0.f, 0.f, 0.f, 0.f};

  for (int k0 = 0; k0 < K; k0 += 32) {
#pragma unroll
    for (int j = 0; j < 2; j++) {
      int c = j * 256 + tid;
      int row = c >> 2, kb = c & 3;
      gl_lds16(A + (size_t)(m0 + row) * K + k0 + kb * 8, As + (size_t)(j * 256 + w * 64) * 8);
      gl_lds16(Bt + (size_t)(n0 + row) * K + k0 + kb * 8, Bs + (size_t)(j * 256 + w * 64) * 8);
    }
    __syncthreads();
    bf16x8_t af[4], bfr[4];
#pragma unroll
    for (int m = 0; m < 4; m++)
      af[m] = *(const bf16x8_t*)(As + (size_t)(wr * 64 + m * 16 + l15) * 32 + l4 * 8);
#pragma unroll
    for (int n = 0; n < 4; n++)
      bfr[n] = *(const bf16x8_t*)(Bs + (size_t)(wc * 64 + n * 16 + l15) * 32 + l4 * 8);
#pragma unroll
    for (int m = 0; m < 4; m++)
#pragma unroll
      for (int n = 0; n < 4; n++) acc[m][n] = mfma16(af[m], bfr[n], acc[m][n]);
    __syncthreads();
  }

  int region = n0 >> 10;  // 0=Q, 1=K, 2=V (region boundaries are 128-aligned)
  if (region < 2) {
    bf16_t* dst = region ? Kr : Qr;
    float qs = region ? 1.0f : QSCALE;
    int h = ((n0 & 1023) + wc * 64) >> 6;  // wave covers exactly one head
#pragma unroll
    for (int m = 0; m < 4; m++)
#pragma unroll
      for (int r = 0; r < 4; r++) {
        int row = m0 + wr * 64 + m * 16 + l4 * 4 + r;
        int b = row >> 11, t = row & 2047;
        size_t obase = ((size_t)(b * NHEAD + h) * T_SEQ + t) * 64;
#pragma unroll
        for (int n = 0; n < 2; n++) {
          int j = n * 16 + l15;
          float c = cs[t * 32 + j], s = sn[t * 32 + j];
          float x1 = acc[m][n][r], x2 = acc[m][n + 2][r];
          dst[obase + j]      = (bf16_t)((x1 * c - x2 * s) * qs);
          dst[obase + 32 + j] = (bf16_t)((x1 * s + x2 * c) * qs);
        }
      }
  } else {
    // V: stage C-tile into LDS transposed, then coalesced store to Vt[bh][d][t]
#pragma unroll
    for (int m = 0; m < 4; m++)
#pragma unroll
      for (int n = 0; n < 4; n++)
#pragma unroll
        for (int r = 0; r < 4; r++)
          vtile[(size_t)(wc * 64 + n * 16 + l15) * 132 + wr * 64 + m * 16 + l4 * 4 + r] =
              (bf16_t)acc[m][n][r];
    __syncthreads();
    int colbase = n0 - 2048;
    int b = m0 >> 11, t0l = m0 & 2047;
#pragma unroll
    for (int p = 0; p < 64; p++) {
      int idx = p * 256 + tid;       // 128x128 elems / 256 threads
      int dl = idx >> 7, tl = idx & 127;
      int col = colbase + dl, h = col >> 6, d = col & 63;
      Vt[((size_t)(b * NHEAD + h) * 64 + d) * T_SEQ + t0l + tl] = vtile[(size_t)dl * 132 + tl];
    }
  }
}

// ---------------- GEMM2: out[4096][1024] = Ob @ woutT^T, fp32 out ----------------
// BM=64 x BN=128 tile -> 512 blocks (2/CU). 4 waves, each 64x32 strip (4x2 frags).
__global__ __launch_bounds__(256) void k_gemm2(const bf16_t* __restrict__ A,
                                               const bf16_t* __restrict__ Bt,
                                               float* __restrict__ C) {
  const int N = 1024, K = 1024;
  __shared__ __align__(16) bf16_t As[64 * 32];
  __shared__ __align__(16) bf16_t Bs[128 * 32];
  int m0 = blockIdx.y * 64, n0 = blockIdx.x * 128;
  int tid = threadIdx.x;
  int lane = tid & 63, w = tid >> 6;
  int l15 = lane & 15, l4 = lane >> 4;

  f32x4_t acc[4][2];
#pragma unroll
  for (int m = 0; m < 4; m++)
#pragma unroll
    for (int n = 0; n < 2; n++) acc[m][n] = (f32x4_t){0.f, 0.f, 0.f, 0.f};

  for (int k0 = 0; k0 < K; k0 += 32) {
    {  // A: 256 chunks of 16B (1/thread)
      int row = tid >> 2, kb = tid & 3;
      gl_lds16(A + (size_t)(m0 + row) * K + k0 + kb * 8, As + (size_t)(w * 64) * 8);
    }
#pragma unroll
    for (int j = 0; j < 2; j++) {  // B: 512 chunks (2/thread)
      int c = j * 256 + tid;
      int row = c >> 2, kb = c & 3;
      gl_lds16(Bt + (size_t)(n0 + row) * K + k0 + kb * 8, Bs + (size_t)(j * 256 + w * 64) * 8);
    }
    __syncthreads();
    bf16x8_t af[4], bfr[2];
#pragma unroll
    for (int m = 0; m < 4; m++)
      af[m] = *(const bf16x8_t*)(As + (size_t)(m * 16 + l15) * 32 + l4 * 8);
#pragma unroll
    for (int n = 0; n < 2; n++)
      bfr[n] = *(const bf16x8_t*)(Bs + (size_t)(w * 32 + n * 16 + l15) * 32 + l4 * 8);
#pragma unroll
    for (int m = 0; m < 4; m++)
#pragma unroll
      for (int n = 0; n < 2; n++) acc[m][n] = mfma16(af[m], bfr[n], acc[m][n]);
    __syncthreads();
  }
#pragma unroll
  for (int m = 0; m < 4; m++)
#pragma unroll
    for (int n = 0; n < 2; n++)
#pragma unroll
      for (int r = 0; r < 4; r++) {
        int row = m0 + m * 16 + l4 * 4 + r;
        int col = n0 + w * 32 + n * 16 + l15;
        C[(size_t)row * N + col] = acc[m][n][r];
      }
}

// ---------------- flash attention ----------------
// grid: 512 blocks (flat). XCD swizzle: each XCD gets 4 contiguous bh (KV set 2MB < L2).
// Block processes q-tiles p and 31-p -> exactly 33 KV-tile iters (perfect balance).
// 3-buffer counted-vmcnt pipeline: [vmcnt(4) -> barrier -> stage(t+2) -> compute(t)],
// each tile's loads get 2 compute phases to land; no full drain in steady state.
__global__ __launch_bounds__(256) void k_attn(const bf16_t* __restrict__ Qr,
                                              const bf16_t* __restrict__ Kr,
                                              const bf16_t* __restrict__ Vt,
                                              bf16_t* __restrict__ Ob) {
  __shared__ __align__(16) bf16_t Ks[3][64 * 64];
  __shared__ __align__(16) bf16_t Vs[3][64 * 64];
  __shared__ __align__(16) bf16_t Ps[64 * 72];  // stride 72: conflict-free b128
  int flat = blockIdx.x;
  int swz = (flat & 7) * 64 + (flat >> 3);  // bijective, 4 contiguous bh per XCD
  int pidx = swz & 15, bh = swz >> 4;
  int b = bh >> 4, h = bh & 15;
  int tid = threadIdx.x, lane = tid & 63, w = tid >> 6;
  int l15 = lane & 15, l4 = lane >> 4;

  const bf16_t* Kbh = Kr + (size_t)bh * T_SEQ * 64;
  const bf16_t* Vbh = Vt + (size_t)bh * 64 * T_SEQ;

  auto stage = [&](int buf, int it) {
    int kb = it * 64;
#pragma unroll
    for (int j = 0; j < 2; j++) {
      int c = j * 256 + tid;
      int row = c >> 3, k8 = c & 7;
      int sk8 = k8 ^ (row & 7);  // pre-swizzled source <-> swizzled read (both-sides rule)
      gl_lds16(Kbh + (size_t)(kb + row) * 64 + sk8 * 8, Ks[buf] + (size_t)(j * 256 + w * 64) * 8);
      gl_lds16(Vbh + (size_t)row * T_SEQ + kb + sk8 * 8, Vs[buf] + (size_t)(j * 256 + w * 64) * 8);
    }
  };

  for (int pass = 0; pass < 2; pass++) {
    int qb = pass ? (31 - pidx) : pidx;
    int q0 = qb * 64;
    int nit = qb + 1;

    // protect K/V buffers from previous pass's in-flight compute
    __builtin_amdgcn_s_barrier();

    // Q fragments (B-operand for swapped QK^T): col=q=l15, k=l4*8+i  (issued oldest)
    bf16x8_t qf[2];
    size_t qbase = ((size_t)bh * T_SEQ + q0 + w * 16 + l15) * 64;
    qf[0] = *(const bf16x8_t*)(Qr + qbase + l4 * 8);
    qf[1] = *(const bf16x8_t*)(Qr + qbase + 32 + l4 * 8);

    stage(0, 0);
    if (nit > 1) stage(1, 1);

    f32x4_t o[4];
#pragma unroll
    for (int n = 0; n < 4; n++) o[n] = (f32x4_t){0.f, 0.f, 0.f, 0.f};
    float m_s = -1e30f, l_s = 0.f;

    for (int it = 0; it < nit; it++) {
      int cur = it % 3;
      // tile `it`'s 4 loads are the oldest outstanding; ≤4 remaining = tile it+1 only
      if (it + 1 < nit) asm volatile("s_waitcnt vmcnt(4)" ::: "memory");
      else              asm volatile("s_waitcnt vmcnt(0)" ::: "memory");
      __builtin_amdgcn_s_barrier();
      if (it + 2 < nit) stage((it + 2) % 3, it + 2);  // overwrites buf of tile it-1 (done)

      // S^T = K Q^T : D[kv_local = l4*4+r (+16n)][q = l15]
      f32x4_t s[4];
      __builtin_amdgcn_s_setprio(1);
#pragma unroll
      for (int n = 0; n < 4; n++) {
        int rowK = n * 16 + l15;
        const bf16_t* kp = Ks[cur] + (size_t)rowK * 64;
        int sw = rowK & 7;
        bf16x8_t kf0 = *(const bf16x8_t*)(kp + (l4 ^ sw) * 8);
        bf16x8_t kf1 = *(const bf16x8_t*)(kp + ((l4 ^ 4) ^ sw) * 8);
        s[n] = (f32x4_t){0.f, 0.f, 0.f, 0.f};
        s[n] = mfma16(kf0, qf[0], s[n]);
        s[n] = mfma16(kf1, qf[1], s[n]);
      }
      __builtin_amdgcn_s_setprio(0);

      if (it == qb) {  // diagonal tile: causal mask
#pragma unroll
        for (int n = 0; n < 4; n++)
#pragma unroll
          for (int r = 0; r < 4; r++)
            if (n * 16 + l4 * 4 + r > w * 16 + l15) s[n][r] = -1e30f;
      }

      // row max: 16 in-lane + 2 shfl (row = q = l15, replicated over l4 groups)
      float t0 = fmaxf(fmaxf(s[0][0], s[0][1]), fmaxf(s[0][2], s[0][3]));
      float t1 = fmaxf(fmaxf(s[1][0], s[1][1]), fmaxf(s[1][2], s[1][3]));
      float t2 = fmaxf(fmaxf(s[2][0], s[2][1]), fmaxf(s[2][2], s[2][3]));
      float t3 = fmaxf(fmaxf(s[3][0], s[3][1]), fmaxf(s[3][2], s[3][3]));
      float mx = fmaxf(fmaxf(t0, t1), fmaxf(t2, t3));
      mx = fmaxf(mx, __shfl_xor(mx, 16, 64));
      mx = fmaxf(mx, __shfl_xor(mx, 32, 64));

      // defer-max (T13): only rescale when the running max grew by > 8 (exp2 domain)
      if (__any(mx - m_s > 8.0f)) {
        float mnew = fmaxf(m_s, mx);
        float alpha = fast_exp2(m_s - mnew);
        m_s = mnew;
        l_s *= alpha;
        float ar[4];
#pragma unroll
        for (int r = 0; r < 4; r++) ar[r] = __shfl(alpha, l4 * 4 + r, 64);
#pragma unroll
        for (int n = 0; n < 4; n++)
#pragma unroll
          for (int r = 0; r < 4; r++) o[n][r] *= ar[r];
      }

      float sum = 0.f;
#pragma unroll
      for (int n = 0; n < 4; n++) {
#pragma unroll
        for (int r = 0; r < 4; r++) s[n][r] = fast_exp2(s[n][r] - m_s);
        bf16x4_t pk = { (bf16_t)s[n][0], (bf16_t)s[n][1], (bf16_t)s[n][2], (bf16_t)s[n][3] };
        *(bf16x4_t*)(Ps + (size_t)(w * 16 + l15) * 72 + n * 16 + l4 * 4) = pk;
        sum += (s[n][0] + s[n][1]) + (s[n][2] + s[n][3]);
      }
      sum += __shfl_xor(sum, 16, 64);
      sum += __shfl_xor(sum, 32, 64);
      l_s += sum;

      // O += P V  (A = P[q][kv] from Ps, B = V[kv][d] from swizzled Vs[d][kv])
      __builtin_amdgcn_s_setprio(1);
#pragma unroll
      for (int ks = 0; ks < 2; ks++) {
        bf16x8_t pa = *(const bf16x8_t*)(Ps + (size_t)(w * 16 + l15) * 72 + ks * 32 + l4 * 8);
#pragma unroll
        for (int n = 0; n < 4; n++) {
          int rowV = n * 16 + l15;
          bf16x8_t vf = *(const bf16x8_t*)(Vs[cur] + (size_t)rowV * 64 +
                                           (((ks * 4 + l4) ^ (rowV & 7)) * 8));
          o[n] = mfma16(pa, vf, o[n]);
        }
      }
      __builtin_amdgcn_s_setprio(0);
    }

    // epilogue: Ob[b*T+q][h*64+d] = O / l
    float linv = 1.0f / l_s;
#pragma unroll
    for (int r = 0; r < 4; r++) {
      float ir = __shfl(linv, l4 * 4 + r, 64);
      int q = q0 + w * 16 + l4 * 4 + r;
      size_t off = ((size_t)(b * T_SEQ + q)) * 1024 + h * 64;
#pragma unroll
      for (int n = 0; n < 4; n++)
        Ob[off + n * 16 + l15] = (bf16_t)(o[n][r] * ir);
    }
  }
}

// ---------------- launch ----------------
extern "C" void kernel_launch(void* const* d_in, const int* in_sizes, int n_in,
                              void* d_out, int out_size, void* d_ws, size_t ws_size,
                              hipStream_t stream) {
  const float* x    = (const float*)d_in[0];
  const float* Wqkv = (const float*)d_in[1];
  const float* Wout = (const float*)d_in[2];
  float* out = (float*)d_out;
  char* ws = (char*)d_ws;

  bf16_t* wqkvT = (bf16_t*)(ws + 0);                       // [3072][1024] 6 MB
  bf16_t* woutT = (bf16_t*)(ws + 6291456);                 // [1024][1024] 2 MB
  bf16_t* xb    = (bf16_t*)(ws + 8388608);                 // [4096][1024] 8 MB (reused as Ob)
  bf16_t* Qr    = (bf16_t*)(ws + 41943040);                // [32][2048][64] 8 MB
  bf16_t* Kr    = (bf16_t*)(ws + 50331648);                // 8 MB
  bf16_t* Vt    = (bf16_t*)(ws + 58720256);                // [32][64][2048] 8 MB
  float*  cs    = (float*)(ws + 67108864);                 // [2048][32] 256 KB
  float*  sn    = (float*)(ws + 67371008);                 // 256 KB
  bf16_t* Ob    = xb;  // xb dead after GEMM1

  k_cast_bf16<<<2048, 256, 0, stream>>>(x, xb, 4096 * 1024);
  k_trans_cast<<<dim3(3072 / 32, 1024 / 32), 256, 0, stream>>>(Wqkv, wqkvT, 1024, 3072);
  k_trans_cast<<<dim3(1024 / 32, 1024 / 32), 256, 0, stream>>>(Wout, woutT, 1024, 1024);
  k_rope_table<<<(T_SEQ * 32) / 256, 256, 0, stream>>>(cs, sn);

  k_gemm_qkv<<<dim3(3072 / 128, 4096 / 128), 256, 0, stream>>>(xb, wqkvT, cs, sn, Qr, Kr, Vt);
  k_attn<<<512, 256, 0, stream>>>(Qr, Kr, Vt, Ob);
  k_gemm2<<<dim3(1024 / 128, 4096 / 64), 256, 0, stream>>>(Ob, woutT, out);
}

// Round 5
// 116.562 us; speedup vs baseline: 2.0028x; 1.0206x over previous
//
#include <hip/hip_runtime.h>
#include <hip/hip_bf16.h>
#include <stdint.h>
#include <math.h>

// B=2, T=2048, D=1024, H=16, DH=64
#define T_SEQ 2048
#define NHEAD 16
#define NBH   32      // B*H
#define BTROW 4096    // B*T

typedef __bf16 bf16_t;
typedef __bf16 bf16x4_t __attribute__((ext_vector_type(4)));
typedef __bf16 bf16x8_t __attribute__((ext_vector_type(8)));
typedef float  f32x4_t  __attribute__((ext_vector_type(4)));

// 0.125 (1/sqrt(64)) * log2(e) — folded into Q so softmax uses exp2 directly
#define QSCALE 0.18033688011112042f

__device__ __forceinline__ f32x4_t mfma16(bf16x8_t a, bf16x8_t b, f32x4_t c) {
  return __builtin_amdgcn_mfma_f32_16x16x32_bf16(a, b, c, 0, 0, 0);
}

__device__ __forceinline__ float fast_exp2(float x) {
#if __has_builtin(__builtin_amdgcn_exp2f)
  return __builtin_amdgcn_exp2f(x);
#else
  return exp2f(x);
#endif
}

// async global->LDS, 16B per lane; lds dest is wave-uniform base (HW adds lane*16)
__device__ __forceinline__ void gl_lds16(const bf16_t* g, bf16_t* l) {
  __builtin_amdgcn_global_load_lds(
      (const __attribute__((address_space(1))) void*)g,
      (__attribute__((address_space(3))) void*)l, 16, 0, 0);
}

// ---------------- cast f32 -> bf16 (vectorized) ----------------
__global__ __launch_bounds__(256) void k_cast_bf16(const float* __restrict__ in,
                                                   bf16_t* __restrict__ out, int n) {
  int tid = blockIdx.x * blockDim.x + threadIdx.x;
  int stride = gridDim.x * blockDim.x;
  for (int i = tid * 4; i < n; i += stride * 4) {
    float4 a = *(const float4*)(in + i);
    bf16x4_t r = { (bf16_t)a.x, (bf16_t)a.y, (bf16_t)a.z, (bf16_t)a.w };
    *(bf16x4_t*)(out + i) = r;
  }
}

// ---------------- transpose + cast: W[K][N] f32 -> WT[N][K] bf16 ----------------
__global__ __launch_bounds__(256) void k_trans_cast(const float* __restrict__ W,
                                                    bf16_t* __restrict__ WT,
                                                    int K, int N) {
  __shared__ float tile[32][33];
  int n0 = blockIdx.x * 32, k0 = blockIdx.y * 32;
  int tx = threadIdx.x & 31, ty = threadIdx.x >> 5;  // 32 x 8
#pragma unroll
  for (int j = 0; j < 4; j++)
    tile[ty + j * 8][tx] = W[(size_t)(k0 + ty + j * 8) * N + n0 + tx];
  __syncthreads();
#pragma unroll
  for (int j = 0; j < 4; j++)
    WT[(size_t)(n0 + ty + j * 8) * K + k0 + tx] = (bf16_t)tile[tx][ty + j * 8];
}

// ---------------- RoPE cos/sin table [T][32] f32 ----------------
__global__ __launch_bounds__(256) void k_rope_table(float* __restrict__ cs,
                                                    float* __restrict__ sn) {
  int i = blockIdx.x * blockDim.x + threadIdx.x;  // t*32 + j
  if (i >= T_SEQ * 32) return;
  int t = i >> 5, j = i & 31;
  float inv = powf(10000.0f, -(float)(2 * j) / 64.0f);
  float f = (float)t * inv;
  cs[i] = cosf(f);
  sn[i] = sinf(f);
}

// ---------------- fused QKV GEMM + RoPE + V-transpose ----------------
__global__ __launch_bounds__(256) void k_gemm_qkv(const bf16_t* __restrict__ A,
                                                  const bf16_t* __restrict__ Bt,
                                                  const float* __restrict__ cs,
                                                  const float* __restrict__ sn,
                                                  bf16_t* __restrict__ Qr,
                                                  bf16_t* __restrict__ Kr,
                                                  bf16_t* __restrict__ Vt) {
  const int K = 1024;
  __shared__ __align__(16) unsigned char smem[128 * 132 * 2];
  bf16_t* As = (bf16_t*)smem;
  bf16_t* Bs = (bf16_t*)(smem + 8192);
  bf16_t* vtile = (bf16_t*)smem;

  int m0 = blockIdx.y * 128, n0 = blockIdx.x * 128;
  int tid = threadIdx.x;
  int lane = tid & 63, w = tid >> 6;
  int wr = w >> 1, wc = w & 1;
  int l15 = lane & 15, l4 = lane >> 4;

  f32x4_t acc[4][4];
#pragma unroll
  for (int m = 0; m < 4; m++)
#pragma unroll
    for (int n = 0; n < 4; n++) acc[m][n] = (f32x4_t){0.f, 0.f, 0.f, 0.f};

  for (int k0 = 0; k0 < K; k0 += 32) {
#pragma unroll
    for (int j = 0; j < 2; j++) {
      int c = j * 256 + tid;
      int row = c >> 2, kb = c & 3;
      gl_lds16(A + (size_t)(m0 + row) * K + k0 + kb * 8, As + (size_t)(j * 256 + w * 64) * 8);
      gl_lds16(Bt + (size_t)(n0 + row) * K + k0 + kb * 8, Bs + (size_t)(j * 256 + w * 64) * 8);
    }
    __syncthreads();
    bf16x8_t af[4], bfr[4];
#pragma unroll
    for (int m = 0; m < 4; m++)
      af[m] = *(const bf16x8_t*)(As + (size_t)(wr * 64 + m * 16 + l15) * 32 + l4 * 8);
#pragma unroll
    for (int n = 0; n < 4; n++)
      bfr[n] = *(const bf16x8_t*)(Bs + (size_t)(wc * 64 + n * 16 + l15) * 32 + l4 * 8);
#pragma unroll
    for (int m = 0; m < 4; m++)
#pragma unroll
      for (int n = 0; n < 4; n++) acc[m][n] = mfma16(af[m], bfr[n], acc[m][n]);
    __syncthreads();
  }

  int region = n0 >> 10;  // 0=Q, 1=K, 2=V
  if (region < 2) {
    bf16_t* dst = region ? Kr : Qr;
    float qs = region ? 1.0f : QSCALE;
    int h = ((n0 & 1023) + wc * 64) >> 6;
#pragma unroll
    for (int m = 0; m < 4; m++)
#pragma unroll
      for (int r = 0; r < 4; r++) {
        int row = m0 + wr * 64 + m * 16 + l4 * 4 + r;
        int b = row >> 11, t = row & 2047;
        size_t obase = ((size_t)(b * NHEAD + h) * T_SEQ + t) * 64;
#pragma unroll
        for (int n = 0; n < 2; n++) {
          int j = n * 16 + l15;
          float c = cs[t * 32 + j], s = sn[t * 32 + j];
          float x1 = acc[m][n][r], x2 = acc[m][n + 2][r];
          dst[obase + j]      = (bf16_t)((x1 * c - x2 * s) * qs);
          dst[obase + 32 + j] = (bf16_t)((x1 * s + x2 * c) * qs);
        }
      }
  } else {
    // V: stage C-tile into LDS transposed, then coalesced store to Vt[bh][d][t]
#pragma unroll
    for (int m = 0; m < 4; m++)
#pragma unroll
      for (int n = 0; n < 4; n++)
#pragma unroll
        for (int r = 0; r < 4; r++)
          vtile[(size_t)(wc * 64 + n * 16 + l15) * 132 + wr * 64 + m * 16 + l4 * 4 + r] =
              (bf16_t)acc[m][n][r];
    __syncthreads();
    int colbase = n0 - 2048;
    int b = m0 >> 11, t0l = m0 & 2047;
#pragma unroll
    for (int p = 0; p < 64; p++) {
      int idx = p * 256 + tid;
      int dl = idx >> 7, tl = idx & 127;
      int col = colbase + dl, h = col >> 6, d = col & 63;
      Vt[((size_t)(b * NHEAD + h) * 64 + d) * T_SEQ + t0l + tl] = vtile[(size_t)dl * 132 + tl];
    }
  }
}

// ---------------- GEMM2: out[4096][1024] = Ob @ woutT^T, fp32 out ----------------
__global__ __launch_bounds__(256) void k_gemm2(const bf16_t* __restrict__ A,
                                               const bf16_t* __restrict__ Bt,
                                               float* __restrict__ C) {
  const int N = 1024, K = 1024;
  __shared__ __align__(16) bf16_t As[64 * 32];
  __shared__ __align__(16) bf16_t Bs[128 * 32];
  int m0 = blockIdx.y * 64, n0 = blockIdx.x * 128;
  int tid = threadIdx.x;
  int lane = tid & 63, w = tid >> 6;
  int l15 = lane & 15, l4 = lane >> 4;

  f32x4_t acc[4][2];
#pragma unroll
  for (int m = 0; m < 4; m++)
#pragma unroll
    for (int n = 0; n < 2; n++) acc[m][n] = (f32x4_t){0.f, 0.f, 0.f, 0.f};

  for (int k0 = 0; k0 < K; k0 += 32) {
    {
      int row = tid >> 2, kb = tid & 3;
      gl_lds16(A + (size_t)(m0 + row) * K + k0 + kb * 8, As + (size_t)(w * 64) * 8);
    }
#pragma unroll
    for (int j = 0; j < 2; j++) {
      int c = j * 256 + tid;
      int row = c >> 2, kb = c & 3;
      gl_lds16(Bt + (size_t)(n0 + row) * K + k0 + kb * 8, Bs + (size_t)(j * 256 + w * 64) * 8);
    }
    __syncthreads();
    bf16x8_t af[4], bfr[2];
#pragma unroll
    for (int m = 0; m < 4; m++)
      af[m] = *(const bf16x8_t*)(As + (size_t)(m * 16 + l15) * 32 + l4 * 8);
#pragma unroll
    for (int n = 0; n < 2; n++)
      bfr[n] = *(const bf16x8_t*)(Bs + (size_t)(w * 32 + n * 16 + l15) * 32 + l4 * 8);
#pragma unroll
    for (int m = 0; m < 4; m++)
#pragma unroll
      for (int n = 0; n < 2; n++) acc[m][n] = mfma16(af[m], bfr[n], acc[m][n]);
    __syncthreads();
  }
#pragma unroll
  for (int m = 0; m < 4; m++)
#pragma unroll
    for (int n = 0; n < 2; n++)
#pragma unroll
      for (int r = 0; r < 4; r++) {
        int row = m0 + m * 16 + l4 * 4 + r;
        int col = n0 + w * 32 + n * 16 + l15;
        C[(size_t)row * N + col] = acc[m][n][r];
      }
}

// ---------------- flash attention (fused-pair, 8 waves) ----------------
// 512 blocks x 512 threads. Waves 0-3 own q-tile pidx, waves 4-7 own q-tile 31-pidx;
// both consume the SAME KV prefix -> one shared staging stream (1 gl_lds/thread/tile).
// 2-deep buffers: [vmcnt(0) -> barrier -> stage(t+1) -> compute(t)], 1 barrier/iter.
// Swapped QK^T, in-register softmax (exp2 domain), defer-max, l-sum via ones-MFMA.
__global__ __launch_bounds__(512, 4) void k_attn(const bf16_t* __restrict__ Qr,
                                                 const bf16_t* __restrict__ Kr,
                                                 const bf16_t* __restrict__ Vt,
                                                 bf16_t* __restrict__ Ob) {
  __shared__ __align__(16) bf16_t Ks[2][64 * 64];
  __shared__ __align__(16) bf16_t Vs[2][64 * 64];
  __shared__ __align__(16) bf16_t Ps[128 * 72];  // 8 waves x 16 rows, stride 72
  int flat = blockIdx.x;
  int swz = (flat & 7) * 64 + (flat >> 3);  // XCD-contiguous bh groups
  int pidx = swz & 15, bh = swz >> 4;
  int b = bh >> 4, h = bh & 15;
  int tid = threadIdx.x, lane = tid & 63, w = tid >> 6;
  int grp = w >> 2, wl = w & 3;
  int l15 = lane & 15, l4 = lane >> 4;

  int qb = grp ? (31 - pidx) : pidx;  // group B (waves 4-7) is always the longer tile
  int nit = qb + 1;
  int nit_max = 32 - pidx;
  int q0 = qb * 64;

  const bf16_t* Kbh = Kr + (size_t)bh * T_SEQ * 64;
  const bf16_t* Vbh = Vt + (size_t)bh * 64 * T_SEQ;

  // per-thread staging chunk (512 chunks of 16B per 8KB tile), pre-swizzled source
  int srow = tid >> 3;
  int sk8 = (tid & 7) ^ (srow & 7);

  auto stage = [&](int buf, int it) {
    int kb = it * 64;
    gl_lds16(Kbh + (size_t)(kb + srow) * 64 + sk8 * 8, Ks[buf] + (size_t)(w * 64) * 8);
    gl_lds16(Vbh + (size_t)srow * T_SEQ + kb + sk8 * 8, Vs[buf] + (size_t)(w * 64) * 8);
  };

  // Q fragments (B-operand for swapped QK^T): col=q=l15, k=l4*8+i
  bf16x8_t qf[2];
  size_t qbase = ((size_t)bh * T_SEQ + q0 + wl * 16 + l15) * 64;
  qf[0] = *(const bf16x8_t*)(Qr + qbase + l4 * 8);
  qf[1] = *(const bf16x8_t*)(Qr + qbase + 32 + l4 * 8);

  bf16x8_t ones;
#pragma unroll
  for (int i = 0; i < 8; i++) ones[i] = (bf16_t)1.0f;

  f32x4_t o[4];
#pragma unroll
  for (int n = 0; n < 4; n++) o[n] = (f32x4_t){0.f, 0.f, 0.f, 0.f};
  f32x4_t ls = (f32x4_t){0.f, 0.f, 0.f, 0.f};  // P row-sums, o-row layout
  float m_s = -1e30f;

  stage(0, 0);

  for (int it = 0; it < nit_max; it++) {
    int cur = it & 1;
    asm volatile("s_waitcnt vmcnt(0)" ::: "memory");  // stage(it) done (own ops)
    __builtin_amdgcn_s_barrier();                     // all waves' stage(it) visible
    if (it + 1 < nit_max) stage(cur ^ 1, it + 1);     // fill other buffer under compute

    if (it < nit) {
      // S^T = K Q^T : D[kv_local = l4*4+r (+16n)][q = l15]
      f32x4_t s[4];
      __builtin_amdgcn_s_setprio(1);
#pragma unroll
      for (int n = 0; n < 4; n++) {
        int rowK = n * 16 + l15;
        const bf16_t* kp = Ks[cur] + (size_t)rowK * 64;
        int sw = rowK & 7;
        bf16x8_t kf0 = *(const bf16x8_t*)(kp + (l4 ^ sw) * 8);
        bf16x8_t kf1 = *(const bf16x8_t*)(kp + ((l4 ^ 4) ^ sw) * 8);
        s[n] = (f32x4_t){0.f, 0.f, 0.f, 0.f};
        s[n] = mfma16(kf0, qf[0], s[n]);
        s[n] = mfma16(kf1, qf[1], s[n]);
      }
      __builtin_amdgcn_s_setprio(0);

      if (it == qb) {  // diagonal tile: causal mask
#pragma unroll
        for (int n = 0; n < 4; n++)
#pragma unroll
          for (int r = 0; r < 4; r++)
            if (n * 16 + l4 * 4 + r > wl * 16 + l15) s[n][r] = -1e30f;
      }

      // row max: 16 in-lane + 2 shfl (row = q = l15)
      float t0 = fmaxf(fmaxf(s[0][0], s[0][1]), fmaxf(s[0][2], s[0][3]));
      float t1 = fmaxf(fmaxf(s[1][0], s[1][1]), fmaxf(s[1][2], s[1][3]));
      float t2 = fmaxf(fmaxf(s[2][0], s[2][1]), fmaxf(s[2][2], s[2][3]));
      float t3 = fmaxf(fmaxf(s[3][0], s[3][1]), fmaxf(s[3][2], s[3][3]));
      float mx = fmaxf(fmaxf(t0, t1), fmaxf(t2, t3));
      mx = fmaxf(mx, __shfl_xor(mx, 16, 64));
      mx = fmaxf(mx, __shfl_xor(mx, 32, 64));

      // defer-max (T13): rescale only when running max grew by > 8 (exp2 domain)
      if (__any(mx - m_s > 8.0f)) {
        float mnew = fmaxf(m_s, mx);
        float alpha = fast_exp2(m_s - mnew);
        m_s = mnew;
        float ar[4];
#pragma unroll
        for (int r = 0; r < 4; r++) ar[r] = __shfl(alpha, l4 * 4 + r, 64);
#pragma unroll
        for (int n = 0; n < 4; n++)
#pragma unroll
          for (int r = 0; r < 4; r++) o[n][r] *= ar[r];
#pragma unroll
        for (int r = 0; r < 4; r++) ls[r] *= ar[r];
      }

#pragma unroll
      for (int n = 0; n < 4; n++) {
#pragma unroll
        for (int r = 0; r < 4; r++) s[n][r] = fast_exp2(s[n][r] - m_s);
        bf16x4_t pk = { (bf16_t)s[n][0], (bf16_t)s[n][1], (bf16_t)s[n][2], (bf16_t)s[n][3] };
        *(bf16x4_t*)(Ps + (size_t)(w * 16 + l15) * 72 + n * 16 + l4 * 4) = pk;
      }

      // O += P V; l-sum via ones-MFMA (row-sums land in o-row layout)
      __builtin_amdgcn_s_setprio(1);
#pragma unroll
      for (int ks = 0; ks < 2; ks++) {
        bf16x8_t pa = *(const bf16x8_t*)(Ps + (size_t)(w * 16 + l15) * 72 + ks * 32 + l4 * 8);
        ls = mfma16(pa, ones, ls);
#pragma unroll
        for (int n = 0; n < 4; n++) {
          int rowV = n * 16 + l15;
          bf16x8_t vf = *(const bf16x8_t*)(Vs[cur] + (size_t)rowV * 64 +
                                           (((ks * 4 + l4) ^ (rowV & 7)) * 8));
          o[n] = mfma16(pa, vf, o[n]);
        }
      }
      __builtin_amdgcn_s_setprio(0);
    }
  }

  // epilogue: Ob[b*T+q][h*64+d] = O / l   (l already in o-row layout — no shuffles)
#pragma unroll
  for (int r = 0; r < 4; r++) {
    float ir = 1.0f / ls[r];
    int q = q0 + wl * 16 + l4 * 4 + r;
    size_t off = ((size_t)(b * T_SEQ + q)) * 1024 + h * 64;
#pragma unroll
    for (int n = 0; n < 4; n++)
      Ob[off + n * 16 + l15] = (bf16_t)(o[n][r] * ir);
  }
}

// ---------------- launch ----------------
extern "C" void kernel_launch(void* const* d_in, const int* in_sizes, int n_in,
                              void* d_out, int out_size, void* d_ws, size_t ws_size,
                              hipStream_t stream) {
  const float* x    = (const float*)d_in[0];
  const float* Wqkv = (const float*)d_in[1];
  const float* Wout = (const float*)d_in[2];
  float* out = (float*)d_out;
  char* ws = (char*)d_ws;

  bf16_t* wqkvT = (bf16_t*)(ws + 0);                       // [3072][1024] 6 MB
  bf16_t* woutT = (bf16_t*)(ws + 6291456);                 // [1024][1024] 2 MB
  bf16_t* xb    = (bf16_t*)(ws + 8388608);                 // [4096][1024] 8 MB (reused as Ob)
  bf16_t* Qr    = (bf16_t*)(ws + 41943040);                // [32][2048][64] 8 MB
  bf16_t* Kr    = (bf16_t*)(ws + 50331648);                // 8 MB
  bf16_t* Vt    = (bf16_t*)(ws + 58720256);                // [32][64][2048] 8 MB
  float*  cs    = (float*)(ws + 67108864);                 // [2048][32] 256 KB
  float*  sn    = (float*)(ws + 67371008);                 // 256 KB
  bf16_t* Ob    = xb;  // xb dead after GEMM1

  k_cast_bf16<<<2048, 256, 0, stream>>>(x, xb, 4096 * 1024);
  k_trans_cast<<<dim3(3072 / 32, 1024 / 32), 256, 0, stream>>>(Wqkv, wqkvT, 1024, 3072);
  k_trans_cast<<<dim3(1024 / 32, 1024 / 32), 256, 0, stream>>>(Wout, woutT, 1024, 1024);
  k_rope_table<<<(T_SEQ * 32) / 256, 256, 0, stream>>>(cs, sn);

  k_gemm_qkv<<<dim3(3072 / 128, 4096 / 128), 256, 0, stream>>>(xb, wqkvT, cs, sn, Qr, Kr, Vt);
  k_attn<<<512, 512, 0, stream>>>(Qr, Kr, Vt, Ob);
  k_gemm2<<<dim3(1024 / 128, 4096 / 64), 256, 0, stream>>>(Ob, woutT, out);
}